// Round 7
// baseline (294.038 us; speedup 1.0000x reference)
//
#include <hip/hip_runtime.h>

typedef __attribute__((ext_vector_type(8))) short short8;
typedef __attribute__((ext_vector_type(4))) float f32x4;
typedef __attribute__((ext_vector_type(4))) int i32x4;
typedef __attribute__((ext_vector_type(4))) unsigned short u16x4;
typedef __attribute__((ext_vector_type(2))) unsigned int u32x2;

#define B_  4
#define N_  2048
#define D_  512
#define H_  8
#define DH_ 64
#define M_  (B_ * N_)   // 8192

__device__ __forceinline__ unsigned short f2bf(float f) {
    union { float f; unsigned u; } un; un.f = f;
    unsigned r = un.u + 0x7FFFu + ((un.u >> 16) & 1u);
    return (unsigned short)(r >> 16);
}
__device__ __forceinline__ float exp2fast(float x) {
#if __has_builtin(__builtin_amdgcn_exp2f)
    return __builtin_amdgcn_exp2f(x);
#else
    float r; asm("v_exp_f32 %0, %1" : "=v"(r) : "v"(x)); return r;
#endif
}
__device__ __forceinline__ unsigned cvtpk_bf16(float lo, float hi) {
    unsigned r;
    asm("v_cvt_pk_bf16_f32 %0, %1, %2" : "=v"(r) : "v"(lo), "v"(hi));
    return r;
}
__device__ __forceinline__ float max3f(float a, float b, float c) {
    return fmaxf(fmaxf(a, b), c);   // clang fuses to v_max3_f32
}

typedef __attribute__((address_space(1))) const void gvoid;
typedef __attribute__((address_space(3))) void svoid;
__device__ __forceinline__ void load16_lds(const void* g, void* s) {
    __builtin_amdgcn_global_load_lds((gvoid*)g, (svoid*)s, 16, 0, 0);
}

// ---------------------------------------------------------------------------
// fp32 -> bf16 conversions for x and the 4 weight matrices, one launch.
// ---------------------------------------------------------------------------
__global__ __launch_bounds__(256) void cvt_all(
    const float* __restrict__ x,
    const float* __restrict__ W0, const float* __restrict__ W1,
    const float* __restrict__ W2, const float* __restrict__ W3,
    unsigned short* __restrict__ xb, unsigned short* __restrict__ Wb) {
    const int bx = blockIdx.x;
    const float* src;
    unsigned short* dst;
    int i;
    if (bx < 4096) {
        src = x; dst = xb;
        i = (bx * 256 + (int)threadIdx.x) * 4;
    } else {
        const int r = bx - 4096;
        const int sel = r >> 8;
        src = (sel == 0) ? W0 : (sel == 1) ? W1 : (sel == 2) ? W2 : W3;
        dst = Wb + (size_t)sel * D_ * D_;
        i = ((r & 255) * 256 + (int)threadIdx.x) * 4;
    }
    f32x4 v = *(const f32x4*)(src + i);
    u16x4 o;
    o[0] = f2bf(v[0]); o[1] = f2bf(v[1]); o[2] = f2bf(v[2]); o[3] = f2bf(v[3]);
    *(u16x4*)(dst + i) = o;
}

// ---------------------------------------------------------------------------
// NT GEMM with global_load_lds(16B) staging + XOR-swizzled LDS.
// Tile 128x128, BK=32, 4 waves; optional fused per-head LN.  (R2/R5 version)
// ---------------------------------------------------------------------------
template <bool F32OUT, bool LNF>
__global__ __launch_bounds__(256, 2) void gemm_nt(
    const unsigned short* __restrict__ A,
    const unsigned short* __restrict__ W,     // [nsel][512][512]
    const float* __restrict__ Bv0,
    const float* __restrict__ Bv1,
    const float* __restrict__ Bv2,
    const float* __restrict__ g0, const float* __restrict__ be0,
    const float* __restrict__ g1, const float* __restrict__ be1,
    unsigned short* __restrict__ outb,
    float* __restrict__ outf)
{
    const int mt = blockIdx.x;
    const int nt = blockIdx.y;
    const int sel = nt >> 2;
    const unsigned short* Wp = W + (size_t)sel * D_ * D_;
    const float* Bv = (sel == 0) ? Bv0 : (sel == 1) ? Bv1 : Bv2;
    const int n0 = (nt & 3) * 128;

    __shared__ __align__(16) unsigned short As[128 * 32];
    __shared__ __align__(16) unsigned short Bs[128 * 32];

    const int tid = threadIdx.x;
    const int w   = tid >> 6;
    const int l   = tid & 63;
    const int l15 = l & 15;
    const int qd  = l >> 4;
    const int wr  = w >> 1;
    const int wc  = w & 1;

    int srow[2], scol[2];
#pragma unroll
    for (int c = 0; c < 2; ++c) {
        const int g   = (w * 2 + c) * 64 + l;
        const int row = g >> 2;
        srow[c] = row;
        scol[c] = ((g & 3) ^ (row & 3)) * 8;
    }

    f32x4 acc[4][4];
#pragma unroll
    for (int i = 0; i < 4; ++i)
#pragma unroll
        for (int j = 0; j < 4; ++j)
            acc[i][j] = (f32x4){0.f, 0.f, 0.f, 0.f};

    const int swz = qd ^ (l15 & 3);

    for (int k0 = 0; k0 < D_; k0 += 32) {
        __syncthreads();
#pragma unroll
        for (int c = 0; c < 2; ++c) {
            load16_lds(A  + (size_t)(mt * 128 + srow[c]) * D_ + k0 + scol[c],
                       As + (w * 2 + c) * 512);
            load16_lds(Wp + (size_t)(n0 + srow[c]) * D_ + k0 + scol[c],
                       Bs + (w * 2 + c) * 512);
        }
        __syncthreads();

        short8 af[4], bfr[4];
#pragma unroll
        for (int rt = 0; rt < 4; ++rt)
            af[rt] = *(const short8*)&As[(wr * 64 + rt * 16 + l15) * 32 + swz * 8];
#pragma unroll
        for (int ct = 0; ct < 4; ++ct)
            bfr[ct] = *(const short8*)&Bs[(wc * 64 + ct * 16 + l15) * 32 + swz * 8];
#pragma unroll
        for (int rt = 0; rt < 4; ++rt)
#pragma unroll
            for (int ct = 0; ct < 4; ++ct)
                acc[rt][ct] = __builtin_amdgcn_mfma_f32_16x16x32_bf16(
                    af[rt], bfr[ct], acc[rt][ct], 0, 0, 0);
    }

    const float* gam = (sel == 0) ? g0 : g1;
    const float* bet = (sel == 0) ? be0 : be1;
    float gv[4], bv2[4];
    if (LNF) {
#pragma unroll
        for (int ct = 0; ct < 4; ++ct) { gv[ct] = gam[ct * 16 + l15]; bv2[ct] = bet[ct * 16 + l15]; }
    }

#pragma unroll
    for (int rt = 0; rt < 4; ++rt) {
        float v[4][4];
#pragma unroll
        for (int ct = 0; ct < 4; ++ct) {
            const float bias = Bv[n0 + wc * 64 + ct * 16 + l15];
#pragma unroll
            for (int r = 0; r < 4; ++r) v[ct][r] = acc[rt][ct][r] + bias;
        }
        if (LNF && sel < 2) {
#pragma unroll
            for (int r = 0; r < 4; ++r) {
                float s  = v[0][r] + v[1][r] + v[2][r] + v[3][r];
                float s2 = v[0][r]*v[0][r] + v[1][r]*v[1][r] + v[2][r]*v[2][r] + v[3][r]*v[3][r];
#pragma unroll
                for (int o = 1; o <= 8; o <<= 1) {
                    s  += __shfl_xor(s, o);
                    s2 += __shfl_xor(s2, o);
                }
                const float mu  = s * 0.015625f;
                const float var = s2 * 0.015625f - mu * mu;
                const float rs  = rsqrtf(var + 1e-6f);
#pragma unroll
                for (int ct = 0; ct < 4; ++ct)
                    v[ct][r] = (v[ct][r] - mu) * rs * gv[ct] + bv2[ct];
            }
        }
#pragma unroll
        for (int ct = 0; ct < 4; ++ct) {
            const int col  = n0 + wc * 64 + ct * 16 + l15;
            const int row0 = mt * 128 + wr * 64 + rt * 16 + qd * 4;
#pragma unroll
            for (int r = 0; r < 4; ++r) {
                const size_t oidx = (size_t)(row0 + r) * D_ + col;
                if (F32OUT) outf[oidx] = v[ct][r];
                else        outb[(size_t)sel * M_ * D_ + oidx] = f2bf(v[ct][r]);
            }
        }
    }
}

// ---------------------------------------------------------------------------
// pack_kv: K -> Kt[b][h][nt][kv64][dh64]; V -> Vt2[b][h][nt][dh64][col'64]
// with kv-column permutation (lane-local P in attn14).
// ---------------------------------------------------------------------------
__global__ __launch_bounds__(256) void pack_kv(
    const unsigned short* __restrict__ K, const unsigned short* __restrict__ V,
    unsigned short* __restrict__ Kt, unsigned short* __restrict__ Vt2)
{
    const int nt = blockIdx.x, b = blockIdx.y;
    const int tid = threadIdx.x;
    __shared__ __align__(16) unsigned short Vl[64][520];

#pragma unroll
    for (int i = 0; i < 16; ++i) {
        const int c = i * 256 + tid;         // 0..4095
        const int row = c >> 6, ch = c & 63;
        const size_t srow = ((size_t)(b * N_ + nt * 64 + row)) * D_ + ch * 8;
        i32x4 kd = *(const i32x4*)(K + srow);
        const int h = ch >> 3, dc = ch & 7;
        *(i32x4*)(Kt + ((((size_t)(b * 8 + h) * 32 + nt) * 64 + row) * 64) + dc * 8) = kd;
        i32x4 vd = *(const i32x4*)(V + srow);
        *(i32x4*)&Vl[row][ch * 8] = vd;
    }
    __syncthreads();
#pragma unroll
    for (int i = 0; i < 16; ++i) {
        const int c = i * 256 + tid;
        const int h = c >> 9, r = c & 511;
        const int dh = r >> 3, kc = r & 7;       // kc: source kv block of 8
        u16x4 o0, o1;
#pragma unroll
        for (int j = 0; j < 4; ++j) o0[j] = Vl[kc * 8 + j][h * 64 + dh];
#pragma unroll
        for (int j = 0; j < 4; ++j) o1[j] = Vl[kc * 8 + 4 + j][h * 64 + dh];
        const int t = kc >> 1;
        const int col0 = (t & 2) * 16 + (kc & 1) * 16 + (t & 1) * 4;
        const size_t rowbase = ((((size_t)(b * 8 + h) * 32 + nt) * 64 + dh) * 64);
        *(u16x4*)(Vt2 + rowbase + col0)     = o0;
        *(u16x4*)(Vt2 + rowbase + col0 + 8) = o1;
    }
}

// ---------------------------------------------------------------------------
// attn14: 4 waves x 32 q-rows (ct=2), 512 blocks. LDS-volume diet:
//  - each wave's full-K read now serves 32 q (2x reuse vs attn12)
//  - V fragments load DIRECTLY from global (L2-resident packed tiles);
//    no V staging, no V ds_reads. LDS carries only K (2x8KB dbuf = 16 KB).
//  - per-CU LDS reads/tile: 256 (attn12) -> 64 ds_read_b128.
// Lane-local P (kv-permuted Vt2), exp2 softmax, defer-max, single-buffered
// fp32 bias issued at iter top (order: bias -> vf -> gll so register waits
// never drain the K staging queue; vmcnt(0) at top retires only old glls).
// ---------------------------------------------------------------------------
__global__ __launch_bounds__(256, 2) void attn14(
    const unsigned short* __restrict__ Qm,
    const unsigned short* __restrict__ Kt,
    const unsigned short* __restrict__ Vt2,
    const float* __restrict__ Bias,          // [b][q][kv] fp32
    unsigned short* __restrict__ AO)
{
    const int qt = blockIdx.x;   // 0..15
    const int h  = blockIdx.y;   // 0..7
    const int b  = blockIdx.z;   // 0..3
    const int w  = threadIdx.x >> 6;   // 0..3
    const int l  = threadIdx.x & 63;
    const int l15 = l & 15;
    const int qd  = l >> 4;
    const int q0 = qt * 128 + w * 32;
    const float L2E = 1.4426950408889634f;

    __shared__ __align__(16) unsigned char smem[16384];   // K0 | K1

    // staging lane constants (row-XOR pre-swizzled global source, linear LDS)
    int soff[2], sc16[2];
#pragma unroll
    for (int i = 0; i < 2; ++i) {
        const int c = (w * 2 + i) * 64 + l;     // 0..511 granules of 16B
        const int srow = c >> 3;
        const int sg   = (c & 7) ^ (srow & 7);
        soff[i] = srow * 64 + sg * 8;           // shorts
        sc16[i] = c * 16;                       // LDS byte offset
    }

    // Q fragments (B-operand): n=q(ct*16+l15), k=dh(hf*32+qd*8+j)
    short8 qf[2][2];
#pragma unroll
    for (int ct = 0; ct < 2; ++ct)
#pragma unroll
        for (int hf = 0; hf < 2; ++hf)
            qf[ct][hf] = *(const short8*)(Qm +
                (size_t)(b * N_ + q0 + ct * 16 + l15) * D_ + h * DH_ + hf * 32 + qd * 8);

    f32x4 Ot[4][2];
#pragma unroll
    for (int rt = 0; rt < 4; ++rt)
#pragma unroll
        for (int ct = 0; ct < 2; ++ct) Ot[rt][ct] = (f32x4){0.f, 0.f, 0.f, 0.f};
    float m_i[2] = {-3.0e38f, -3.0e38f};
    f32x4 li4[2];
    li4[0] = (f32x4){0.f, 0.f, 0.f, 0.f};
    li4[1] = (f32x4){0.f, 0.f, 0.f, 0.f};

    const unsigned short* Ktile0 = Kt  + (((size_t)(b * 8 + h) * 32) * 64) * 64;
    const unsigned short* Vtile0 = Vt2 + (((size_t)(b * 8 + h) * 32) * 64) * 64;
    const float* bQ0 = Bias + ((size_t)b * N_ + q0 + l15) * N_;
    const float* bQ1 = Bias + ((size_t)b * N_ + q0 + 16 + l15) * N_;

    // prologue: stage K tile 0 into buf0
    load16_lds(Ktile0 + soff[0], smem + sc16[0]);
    load16_lds(Ktile0 + soff[1], smem + sc16[1]);

// One kv-tile iteration. CUR = LDS K buffer (compile-time).
// vmcnt at loop top: only the 2 gll(KT) (issued a full iter ago) outstanding.
// Issue order in-iter: bias(KT) x8 -> vf(KT) x8 -> gll(KT+1) x2.
// softmax's auto-wait for bias = vmcnt(10); PV's wait for vf = vmcnt(2);
// the K staging glls stay in flight across both.
#define ATTN_ITER(KT, CUR) do {                                                \
    unsigned char* Kbc = smem + (CUR) * 8192;                                  \
    asm volatile("s_waitcnt vmcnt(0)" ::: "memory");                           \
    __builtin_amdgcn_s_barrier();                                              \
    __builtin_amdgcn_sched_barrier(0);                                         \
    f32x4 br[4][2];                                                            \
    _Pragma("unroll")                                                          \
    for (int rt = 0; rt < 4; ++rt) {                                           \
        br[rt][0] = *(const f32x4*)(bQ0 + (size_t)(KT) * 64 + rt * 16 + qd * 4); \
        br[rt][1] = *(const f32x4*)(bQ1 + (size_t)(KT) * 64 + rt * 16 + qd * 4); \
    }                                                                          \
    asm volatile("" ::: "memory");  /* pin: bias before vf */                  \
    short8 vf[4][2];                                                           \
    {                                                                          \
        const unsigned short* Vtl = Vtile0 + (size_t)(KT) * 4096;              \
        _Pragma("unroll")                                                      \
        for (int rt = 0; rt < 4; ++rt)                                         \
            _Pragma("unroll")                                                  \
            for (int hf = 0; hf < 2; ++hf)                                     \
                vf[rt][hf] = *(const short8*)(Vtl + (rt * 16 + l15) * 64 +     \
                                              hf * 32 + qd * 8);               \
    }                                                                          \
    asm volatile("" ::: "memory");  /* pin: vf before gll */                   \
    if ((KT) < 31) {                                                           \
        const unsigned short* Kn = Ktile0 + (size_t)((KT) + 1) * 4096;         \
        unsigned char* KbN = smem + (((CUR) ^ 1)) * 8192;                      \
        load16_lds(Kn + soff[0], KbN + sc16[0]);                               \
        load16_lds(Kn + soff[1], KbN + sc16[1]);                               \
    }                                                                          \
    asm volatile("" ::: "memory");                                             \
    short8 kf[4][2];                                                           \
    _Pragma("unroll")                                                          \
    for (int rt = 0; rt < 4; ++rt) {                                           \
        const int kv = rt * 16 + l15;                                          \
        _Pragma("unroll")                                                      \
        for (int hf = 0; hf < 2; ++hf) {                                       \
            const int cidx = (hf * 4 + qd) ^ (kv & 7);                         \
            kf[rt][hf] = *(const short8*)(Kbc + kv * 128 + cidx * 16);         \
        }                                                                      \
    }                                                                          \
    f32x4 St[4][2];                                                            \
    __builtin_amdgcn_s_setprio(1);                                             \
    _Pragma("unroll")                                                          \
    for (int rt = 0; rt < 4; ++rt)                                             \
        _Pragma("unroll")                                                      \
        for (int ct = 0; ct < 2; ++ct) {                                       \
            f32x4 v = (f32x4){0.f, 0.f, 0.f, 0.f};                             \
            v = __builtin_amdgcn_mfma_f32_16x16x32_bf16(kf[rt][0], qf[ct][0], v, 0, 0, 0); \
            v = __builtin_amdgcn_mfma_f32_16x16x32_bf16(kf[rt][1], qf[ct][1], v, 0, 0, 0); \
            St[rt][ct] = v;                                                    \
        }                                                                      \
    __builtin_amdgcn_s_setprio(0);                                             \
    _Pragma("unroll")                                                          \
    for (int ct = 0; ct < 2; ++ct) {                                           \
        f32x4 sv[4];                                                           \
        _Pragma("unroll")                                                      \
        for (int rt = 0; rt < 4; ++rt)                                         \
            sv[rt] = St[rt][ct] * 0.125f + br[rt][ct];                         \
        float mx0 = max3f(sv[0][0], sv[0][1], sv[0][2]);                       \
        float mx1 = max3f(sv[0][3], sv[1][0], sv[1][1]);                       \
        float mx2 = max3f(sv[1][2], sv[1][3], sv[2][0]);                       \
        float mx3 = max3f(sv[2][1], sv[2][2], sv[2][3]);                       \
        mx0 = max3f(mx0, sv[3][0], sv[3][1]);                                  \
        mx1 = max3f(mx1, sv[3][2], sv[3][3]);                                  \
        float mx = fmaxf(max3f(mx0, mx1, mx2), mx3);                           \
        mx = fmaxf(mx, __shfl_xor(mx, 16));                                    \
        mx = fmaxf(mx, __shfl_xor(mx, 32));                                    \
        if (__any(mx > m_i[ct] + 8.0f)) {                                      \
            const float mnew  = fmaxf(m_i[ct], mx);                            \
            const float alpha = exp2fast((m_i[ct] - mnew) * L2E);              \
            m_i[ct] = mnew;                                                    \
            li4[ct] *= alpha;                                                  \
            _Pragma("unroll")                                                  \
            for (int rt = 0; rt < 4; ++rt) Ot[rt][ct] *= alpha;                \
        }                                                                      \
        const float mL = m_i[ct] * L2E;                                        \
        f32x4 p[4];                                                            \
        _Pragma("unroll")                                                      \
        for (int rt = 0; rt < 4; ++rt) {                                       \
            f32x4 e = sv[rt] * L2E - mL;                                       \
            p[rt][0] = exp2fast(e[0]); p[rt][1] = exp2fast(e[1]);              \
            p[rt][2] = exp2fast(e[2]); p[rt][3] = exp2fast(e[3]);              \
        }                                                                      \
        li4[ct] += (p[0] + p[1]) + (p[2] + p[3]);                              \
        union { unsigned u[4]; short8 s; } pk0, pk1;                           \
        pk0.u[0] = cvtpk_bf16(p[0][0], p[0][1]);                               \
        pk0.u[1] = cvtpk_bf16(p[0][2], p[0][3]);                               \
        pk0.u[2] = cvtpk_bf16(p[1][0], p[1][1]);                               \
        pk0.u[3] = cvtpk_bf16(p[1][2], p[1][3]);                               \
        pk1.u[0] = cvtpk_bf16(p[2][0], p[2][1]);                               \
        pk1.u[1] = cvtpk_bf16(p[2][2], p[2][3]);                               \
        pk1.u[2] = cvtpk_bf16(p[3][0], p[3][1]);                               \
        pk1.u[3] = cvtpk_bf16(p[3][2], p[3][3]);                               \
        __builtin_amdgcn_s_setprio(1);                                         \
        _Pragma("unroll")                                                      \
        for (int rt = 0; rt < 4; ++rt) {                                       \
            Ot[rt][ct] = __builtin_amdgcn_mfma_f32_16x16x32_bf16(vf[rt][0], pk0.s, Ot[rt][ct], 0, 0, 0); \
            Ot[rt][ct] = __builtin_amdgcn_mfma_f32_16x16x32_bf16(vf[rt][1], pk1.s, Ot[rt][ct], 0, 0, 0); \
        }                                                                      \
        __builtin_amdgcn_s_setprio(0);                                         \
    }                                                                          \
} while (0)

    for (int kt2 = 0; kt2 < 16; ++kt2) {
        ATTN_ITER(kt2 * 2,     0);
        ATTN_ITER(kt2 * 2 + 1, 1);
    }
#undef ATTN_ITER

    // epilogue
#pragma unroll
    for (int ct = 0; ct < 2; ++ct) {
        float l_i = (li4[ct][0] + li4[ct][1]) + (li4[ct][2] + li4[ct][3]);
        l_i += __shfl_xor(l_i, 16);
        l_i += __shfl_xor(l_i, 32);
        const float inv = 1.f / l_i;
        const int q = q0 + ct * 16 + l15;
#pragma unroll
        for (int rt = 0; rt < 4; ++rt) {
            u16x4 ob;
#pragma unroll
            for (int r = 0; r < 4; ++r) ob[r] = f2bf(Ot[rt][ct][r] * inv);
            *(u16x4*)(AO + (size_t)(b * N_ + q) * D_ + h * DH_ + rt * 16 + qd * 4) = ob;
        }
    }
}

// ---------------------------------------------------------------------------
extern "C" void kernel_launch(void* const* d_in, const int* in_sizes, int n_in,
                              void* d_out, int out_size, void* d_ws, size_t ws_size,
                              hipStream_t stream) {
    const float* x  = (const float*)d_in[0];
    const float* ab = (const float*)d_in[1];
    const float* Wq = (const float*)d_in[2];
    const float* bq = (const float*)d_in[3];
    const float* Wk = (const float*)d_in[4];
    const float* bk = (const float*)d_in[5];
    const float* Wv = (const float*)d_in[6];
    const float* bv = (const float*)d_in[7];
    const float* Wo = (const float*)d_in[8];
    const float* bo = (const float*)d_in[9];
    const float* qg = (const float*)d_in[10];
    const float* qb = (const float*)d_in[11];
    const float* kg = (const float*)d_in[12];
    const float* kb = (const float*)d_in[13];

    // ws layout (bf16 elements)
    unsigned short* xb  = (unsigned short*)d_ws;                // [8192][512]
    unsigned short* Wb  = xb  + (size_t)M_ * D_;                // [4][512][512]
    unsigned short* Y   = Wb  + (size_t)4 * D_ * D_;            // [3][8192][512]
    unsigned short* Kt  = Y   + (size_t)3 * M_ * D_;            // [4][8][32][64][64]
    unsigned short* Vt2 = Kt  + (size_t)M_ * D_;                // [4][8][32][64][64] (kv-permuted)
    unsigned short* AO  = Vt2 + (size_t)M_ * D_;                // [8192][512]
    float* out = (float*)d_out;

    cvt_all<<<dim3(5120), dim3(256), 0, stream>>>(x, Wq, Wk, Wv, Wo, xb, Wb);

    // QKV projection with fused per-head LN on q,k
    gemm_nt<false, true><<<dim3(64, 12), dim3(256), 0, stream>>>(
        xb, Wb, bq, bk, bv, qg, qb, kg, kb, Y, nullptr);

    // pack K,V into contiguous per-head tiles (V transposed + kv-permuted)
    pack_kv<<<dim3(32, 4), dim3(256), 0, stream>>>(
        Y + (size_t)M_ * D_, Y + (size_t)2 * M_ * D_, Kt, Vt2);

    // attention (LDS-volume diet: K-only LDS, V from global, ct=2)
    attn14<<<dim3(16, 8, 4), dim3(256), 0, stream>>>(
        Y, Kt, Vt2, ab, AO);

    // output projection -> d_out (fp32)
    gemm_nt<true, false><<<dim3(64, 4), dim3(256), 0, stream>>>(
        AO, Wb + (size_t)3 * D_ * D_, bo, bo, bo,
        nullptr, nullptr, nullptr, nullptr, nullptr, out);
}

// Round 8
// 255.343 us; speedup vs baseline: 1.1515x; 1.1515x over previous
//
#include <hip/hip_runtime.h>

typedef __attribute__((ext_vector_type(8))) short short8;
typedef __attribute__((ext_vector_type(4))) float f32x4;
typedef __attribute__((ext_vector_type(4))) int i32x4;
typedef __attribute__((ext_vector_type(4))) unsigned short u16x4;
typedef __attribute__((ext_vector_type(2))) unsigned int u32x2;

#define B_  4
#define N_  2048
#define D_  512
#define H_  8
#define DH_ 64
#define M_  (B_ * N_)   // 8192

__device__ __forceinline__ unsigned short f2bf(float f) {
    union { float f; unsigned u; } un; un.f = f;
    unsigned r = un.u + 0x7FFFu + ((un.u >> 16) & 1u);
    return (unsigned short)(r >> 16);
}
__device__ __forceinline__ float exp2fast(float x) {
#if __has_builtin(__builtin_amdgcn_exp2f)
    return __builtin_amdgcn_exp2f(x);
#else
    float r; asm("v_exp_f32 %0, %1" : "=v"(r) : "v"(x)); return r;
#endif
}
// v_cvt_pk_bf16_f32: packs two f32 -> bf16x2 (RNE), verified gfx950
__device__ __forceinline__ unsigned cvtpk_bf16(float lo, float hi) {
    unsigned r;
    asm("v_cvt_pk_bf16_f32 %0, %1, %2" : "=v"(r) : "v"(lo), "v"(hi));
    return r;
}
__device__ __forceinline__ float max3f(float a, float b, float c) {
    return fmaxf(fmaxf(a, b), c);   // clang fuses to v_max3_f32
}

typedef __attribute__((address_space(1))) const void gvoid;
typedef __attribute__((address_space(3))) void svoid;
__device__ __forceinline__ void load16_lds(const void* g, void* s) {
    __builtin_amdgcn_global_load_lds((gvoid*)g, (svoid*)s, 16, 0, 0);
}

// ---------------------------------------------------------------------------
// cvt_w: fp32 -> bf16 for the 4 weight matrices only (x converts inline in
// the QKV GEMM's A-staging now). 4 x 512 x 512 elems, grid 1024.
// ---------------------------------------------------------------------------
__global__ __launch_bounds__(256) void cvt_w(
    const float* __restrict__ W0, const float* __restrict__ W1,
    const float* __restrict__ W2, const float* __restrict__ W3,
    unsigned short* __restrict__ Wb) {
    const int bx = blockIdx.x;           // 0..1023
    const int sel = bx >> 8;
    const float* src = (sel == 0) ? W0 : (sel == 1) ? W1 : (sel == 2) ? W2 : W3;
    unsigned short* dst = Wb + (size_t)sel * D_ * D_;
    const int i = ((bx & 255) * 256 + (int)threadIdx.x) * 4;
    f32x4 v = *(const f32x4*)(src + i);
    u16x4 o;
    o[0] = f2bf(v[0]); o[1] = f2bf(v[1]); o[2] = f2bf(v[2]); o[3] = f2bf(v[3]);
    *(u16x4*)(dst + i) = o;
}

// ---------------------------------------------------------------------------
// NT GEMM with LDS staging + XOR-swizzled layout. Tile 128x128, BK=32,
// 4 waves; optional fused per-head LN.
// AF32: A-operand is fp32 in global; reg-stage with inline cvt_pk (saves the
//       separate 100MB conversion pass). Otherwise A is bf16 via gll.
// ---------------------------------------------------------------------------
template <bool AF32, bool F32OUT, bool LNF>
__global__ __launch_bounds__(256, 2) void gemm_nt(
    const unsigned short* __restrict__ A,     // bf16 A (when !AF32)
    const float* __restrict__ Af,             // fp32 A (when AF32)
    const unsigned short* __restrict__ W,     // [nsel][512][512] bf16
    const float* __restrict__ Bv0,
    const float* __restrict__ Bv1,
    const float* __restrict__ Bv2,
    const float* __restrict__ g0, const float* __restrict__ be0,
    const float* __restrict__ g1, const float* __restrict__ be1,
    unsigned short* __restrict__ outb,
    float* __restrict__ outf)
{
    const int mt = blockIdx.x;
    const int nt = blockIdx.y;
    const int sel = nt >> 2;
    const unsigned short* Wp = W + (size_t)sel * D_ * D_;
    const float* Bv = (sel == 0) ? Bv0 : (sel == 1) ? Bv1 : Bv2;
    const int n0 = (nt & 3) * 128;

    __shared__ __align__(16) unsigned short As[128 * 32];
    __shared__ __align__(16) unsigned short Bs[128 * 32];

    const int tid = threadIdx.x;
    const int w   = tid >> 6;
    const int l   = tid & 63;
    const int l15 = l & 15;
    const int qd  = l >> 4;
    const int wr  = w >> 1;
    const int wc  = w & 1;

    int srow[2], scol[2];
#pragma unroll
    for (int c = 0; c < 2; ++c) {
        const int g   = (w * 2 + c) * 64 + l;
        const int row = g >> 2;
        srow[c] = row;
        scol[c] = ((g & 3) ^ (row & 3)) * 8;
    }

    f32x4 acc[4][4];
#pragma unroll
    for (int i = 0; i < 4; ++i)
#pragma unroll
        for (int j = 0; j < 4; ++j)
            acc[i][j] = (f32x4){0.f, 0.f, 0.f, 0.f};

    const int swz = qd ^ (l15 & 3);

    for (int k0 = 0; k0 < D_; k0 += 32) {
        __syncthreads();
#pragma unroll
        for (int c = 0; c < 2; ++c) {
            if (AF32) {
                const int g = (w * 2 + c) * 64 + l;
                const float* srcA = Af + (size_t)(mt * 128 + srow[c]) * D_ + k0 + scol[c];
                f32x4 v0 = *(const f32x4*)srcA;
                f32x4 v1 = *(const f32x4*)(srcA + 4);
                union { unsigned u[4]; short8 s; } pk;
                pk.u[0] = cvtpk_bf16(v0[0], v0[1]);
                pk.u[1] = cvtpk_bf16(v0[2], v0[3]);
                pk.u[2] = cvtpk_bf16(v1[0], v1[1]);
                pk.u[3] = cvtpk_bf16(v1[2], v1[3]);
                *(short8*)&As[g * 8] = pk.s;
            } else {
                load16_lds(A + (size_t)(mt * 128 + srow[c]) * D_ + k0 + scol[c],
                           As + (w * 2 + c) * 512);
            }
            load16_lds(Wp + (size_t)(n0 + srow[c]) * D_ + k0 + scol[c],
                       Bs + (w * 2 + c) * 512);
        }
        __syncthreads();

        short8 af[4], bfr[4];
#pragma unroll
        for (int rt = 0; rt < 4; ++rt)
            af[rt] = *(const short8*)&As[(wr * 64 + rt * 16 + l15) * 32 + swz * 8];
#pragma unroll
        for (int ct = 0; ct < 4; ++ct)
            bfr[ct] = *(const short8*)&Bs[(wc * 64 + ct * 16 + l15) * 32 + swz * 8];
#pragma unroll
        for (int rt = 0; rt < 4; ++rt)
#pragma unroll
            for (int ct = 0; ct < 4; ++ct)
                acc[rt][ct] = __builtin_amdgcn_mfma_f32_16x16x32_bf16(
                    af[rt], bfr[ct], acc[rt][ct], 0, 0, 0);
    }

    const float* gam = (sel == 0) ? g0 : g1;
    const float* bet = (sel == 0) ? be0 : be1;
    float gv[4], bv2[4];
    if (LNF) {
#pragma unroll
        for (int ct = 0; ct < 4; ++ct) { gv[ct] = gam[ct * 16 + l15]; bv2[ct] = bet[ct * 16 + l15]; }
    }

#pragma unroll
    for (int rt = 0; rt < 4; ++rt) {
        float v[4][4];
#pragma unroll
        for (int ct = 0; ct < 4; ++ct) {
            const float bias = Bv[n0 + wc * 64 + ct * 16 + l15];
#pragma unroll
            for (int r = 0; r < 4; ++r) v[ct][r] = acc[rt][ct][r] + bias;
        }
        if (LNF && sel < 2) {
#pragma unroll
            for (int r = 0; r < 4; ++r) {
                float s  = v[0][r] + v[1][r] + v[2][r] + v[3][r];
                float s2 = v[0][r]*v[0][r] + v[1][r]*v[1][r] + v[2][r]*v[2][r] + v[3][r]*v[3][r];
#pragma unroll
                for (int o = 1; o <= 8; o <<= 1) {
                    s  += __shfl_xor(s, o);
                    s2 += __shfl_xor(s2, o);
                }
                const float mu  = s * 0.015625f;
                const float var = s2 * 0.015625f - mu * mu;
                const float rs  = rsqrtf(var + 1e-6f);
#pragma unroll
                for (int ct = 0; ct < 4; ++ct)
                    v[ct][r] = (v[ct][r] - mu) * rs * gv[ct] + bv2[ct];
            }
        }
#pragma unroll
        for (int ct = 0; ct < 4; ++ct) {
            const int col  = n0 + wc * 64 + ct * 16 + l15;
            const int row0 = mt * 128 + wr * 64 + rt * 16 + qd * 4;
#pragma unroll
            for (int r = 0; r < 4; ++r) {
                const size_t oidx = (size_t)(row0 + r) * D_ + col;
                if (F32OUT) outf[oidx] = v[ct][r];
                else        outb[(size_t)sel * M_ * D_ + oidx] = f2bf(v[ct][r]);
            }
        }
    }
}

// ---------------------------------------------------------------------------
// pack_kv: K -> Kt[b][h][nt][kv64][dh64]; V -> Vt2[b][h][nt][dh64][col'64]
// with kv-column permutation (lane-local P in attn12).
// ---------------------------------------------------------------------------
__global__ __launch_bounds__(256) void pack_kv(
    const unsigned short* __restrict__ K, const unsigned short* __restrict__ V,
    unsigned short* __restrict__ Kt, unsigned short* __restrict__ Vt2)
{
    const int nt = blockIdx.x, b = blockIdx.y;
    const int tid = threadIdx.x;
    __shared__ __align__(16) unsigned short Vl[64][520];

#pragma unroll
    for (int i = 0; i < 16; ++i) {
        const int c = i * 256 + tid;         // 0..4095
        const int row = c >> 6, ch = c & 63;
        const size_t srow = ((size_t)(b * N_ + nt * 64 + row)) * D_ + ch * 8;
        i32x4 kd = *(const i32x4*)(K + srow);
        const int h = ch >> 3, dc = ch & 7;
        *(i32x4*)(Kt + ((((size_t)(b * 8 + h) * 32 + nt) * 64 + row) * 64) + dc * 8) = kd;
        i32x4 vd = *(const i32x4*)(V + srow);
        *(i32x4*)&Vl[row][ch * 8] = vd;
    }
    __syncthreads();
#pragma unroll
    for (int i = 0; i < 16; ++i) {
        const int c = i * 256 + tid;
        const int h = c >> 9, r = c & 511;
        const int dh = r >> 3, kc = r & 7;       // kc: source kv block of 8
        u16x4 o0, o1;
#pragma unroll
        for (int j = 0; j < 4; ++j) o0[j] = Vl[kc * 8 + j][h * 64 + dh];
#pragma unroll
        for (int j = 0; j < 4; ++j) o1[j] = Vl[kc * 8 + 4 + j][h * 64 + dh];
        const int t = kc >> 1;
        const int col0 = (t & 2) * 16 + (kc & 1) * 16 + (t & 1) * 4;
        const size_t rowbase = ((((size_t)(b * 8 + h) * 32 + nt) * 64 + dh) * 64);
        *(u16x4*)(Vt2 + rowbase + col0)     = o0;
        *(u16x4*)(Vt2 + rowbase + col0 + 8) = o1;
    }
}

// ---------------------------------------------------------------------------
// attn12 (R5 best-known, verbatim): 8 waves x 16 q-rows, shared K/V LDS
// double-buffer (counted vmcnt(4), 1 barrier/iter), fp32 bias reg-prefetch,
// exp2-domain softmax, defer-max, lane-local P via kv-permuted Vt2.
// LDS: K0 8K | V0 8K | K1 8K | V1 8K = 32768 B.
// ---------------------------------------------------------------------------
__global__ __launch_bounds__(512, 4) void attn12(
    const unsigned short* __restrict__ Qm,
    const unsigned short* __restrict__ Kt,
    const unsigned short* __restrict__ Vt2,
    const float* __restrict__ Bias,          // [b][q][kv] fp32
    unsigned short* __restrict__ AO)
{
    const int qt = blockIdx.x;   // 0..15
    const int h  = blockIdx.y;   // 0..7
    const int b  = blockIdx.z;   // 0..3
    const int w  = threadIdx.x >> 6;   // 0..7
    const int l  = threadIdx.x & 63;
    const int l15 = l & 15;
    const int qd  = l >> 4;
    const int q0 = qt * 128 + w * 16;
    const float L2E = 1.4426950408889634f;

    __shared__ __align__(16) unsigned char smem[32768];

    // staging lane constants (row-XOR pre-swizzled global source, linear LDS)
    const int c    = w * 64 + l;            // 0..511 granules of 16B
    const int srow = c >> 3;
    const int sg   = (c & 7) ^ (srow & 7);
    const int soff = srow * 64 + sg * 8;    // shorts
    const int sc16 = c * 16;                // LDS byte offset

    // Q fragments (B-operand): n=q(l15), k=dh(hf*32+qd*8+j)
    short8 qf[2];
#pragma unroll
    for (int hf = 0; hf < 2; ++hf)
        qf[hf] = *(const short8*)(Qm +
            (size_t)(b * N_ + q0 + l15) * D_ + h * DH_ + hf * 32 + qd * 8);

    f32x4 Ot[4];
#pragma unroll
    for (int rt = 0; rt < 4; ++rt) Ot[rt] = (f32x4){0.f, 0.f, 0.f, 0.f};
    float m_i = -3.0e38f;
    f32x4 li4 = (f32x4){0.f, 0.f, 0.f, 0.f};

    const unsigned short* Ktile0 = Kt  + (((size_t)(b * 8 + h) * 32) * 64) * 64;
    const unsigned short* Vtile0 = Vt2 + (((size_t)(b * 8 + h) * 32) * 64) * 64;
    const float* biasQ = Bias + ((size_t)b * N_ + q0 + l15) * N_;

    // prologue: stage tile 0 K/V into buf0, bias tile 0 into brA, then drain
    load16_lds(Ktile0 + soff, smem + sc16);
    load16_lds(Vtile0 + soff, smem + 8192 + sc16);
    f32x4 brA[4], brB[4];
#pragma unroll
    for (int rt = 0; rt < 4; ++rt)
        brA[rt] = *(const f32x4*)(biasQ + rt * 16 + qd * 4);
    asm volatile("s_waitcnt vmcnt(0)" ::: "memory");

#define ATTN_ITER(KT, CUR, BRC, BRN) do {                                      \
    unsigned char* Kbc = smem + (CUR) * 16384;                                 \
    unsigned char* Vbc = Kbc + 8192;                                           \
    asm volatile("s_waitcnt vmcnt(4)" ::: "memory");                           \
    __builtin_amdgcn_s_barrier();                                              \
    __builtin_amdgcn_sched_barrier(0);                                         \
    if ((KT) < 31) {                                                           \
        const unsigned short* Kn = Ktile0 + (size_t)((KT) + 1) * 4096;         \
        const unsigned short* Vn = Vtile0 + (size_t)((KT) + 1) * 4096;         \
        unsigned char* KbN = smem + (((CUR) ^ 1)) * 16384;                     \
        load16_lds(Kn + soff, KbN + sc16);                                     \
        load16_lds(Vn + soff, KbN + 8192 + sc16);                              \
    }                                                                          \
    asm volatile("" ::: "memory");  /* pin order: gll before bias loads */     \
    {                                                                          \
        const float* Bn = biasQ + (size_t)(((KT) < 31) ? (KT) + 1 : 31) * 64;  \
        _Pragma("unroll")                                                      \
        for (int rt = 0; rt < 4; ++rt)                                         \
            BRN[rt] = *(const f32x4*)(Bn + rt * 16 + qd * 4);                  \
    }                                                                          \
    short8 kf[4][2];                                                           \
    _Pragma("unroll")                                                          \
    for (int rt = 0; rt < 4; ++rt) {                                           \
        const int kv = rt * 16 + l15;                                          \
        _Pragma("unroll")                                                      \
        for (int hf = 0; hf < 2; ++hf) {                                       \
            const int cidx = (hf * 4 + qd) ^ (kv & 7);                         \
            kf[rt][hf] = *(const short8*)(Kbc + kv * 128 + cidx * 16);         \
        }                                                                      \
    }                                                                          \
    f32x4 St[4];                                                               \
    __builtin_amdgcn_s_setprio(1);                                             \
    _Pragma("unroll")                                                          \
    for (int rt = 0; rt < 4; ++rt) {                                           \
        f32x4 v = (f32x4){0.f, 0.f, 0.f, 0.f};                                 \
        v = __builtin_amdgcn_mfma_f32_16x16x32_bf16(kf[rt][0], qf[0], v, 0, 0, 0); \
        v = __builtin_amdgcn_mfma_f32_16x16x32_bf16(kf[rt][1], qf[1], v, 0, 0, 0); \
        St[rt] = v;                                                            \
    }                                                                          \
    __builtin_amdgcn_s_setprio(0);                                             \
    short8 vf[4][2];                                                           \
    _Pragma("unroll")                                                          \
    for (int rt = 0; rt < 4; ++rt) {                                           \
        const int dh = rt * 16 + l15;                                          \
        _Pragma("unroll")                                                      \
        for (int hf = 0; hf < 2; ++hf) {                                       \
            const int cidx = (hf * 4 + qd) ^ (dh & 7);                         \
            vf[rt][hf] = *(const short8*)(Vbc + dh * 128 + cidx * 16);         \
        }                                                                      \
    }                                                                          \
    unsigned wq[4][2];                                                         \
    {                                                                          \
        f32x4 sv[4];                                                           \
        _Pragma("unroll")                                                      \
        for (int rt = 0; rt < 4; ++rt)                                         \
            sv[rt] = St[rt] * 0.125f + BRC[rt];                                \
        float mx0 = max3f(sv[0][0], sv[0][1], sv[0][2]);                       \
        float mx1 = max3f(sv[0][3], sv[1][0], sv[1][1]);                       \
        float mx2 = max3f(sv[1][2], sv[1][3], sv[2][0]);                       \
        float mx3 = max3f(sv[2][1], sv[2][2], sv[2][3]);                       \
        mx0 = max3f(mx0, sv[3][0], sv[3][1]);                                  \
        mx1 = max3f(mx1, sv[3][2], sv[3][3]);                                  \
        float mx = fmaxf(max3f(mx0, mx1, mx2), mx3);                           \
        mx = fmaxf(mx, __shfl_xor(mx, 16));                                    \
        mx = fmaxf(mx, __shfl_xor(mx, 32));                                    \
        if (__any(mx > m_i + 8.0f)) {                                          \
            const float mnew  = fmaxf(m_i, mx);                                \
            const float alpha = exp2fast((m_i - mnew) * L2E);                  \
            m_i = mnew;                                                        \
            li4 *= alpha;                                                      \
            _Pragma("unroll")                                                  \
            for (int rt = 0; rt < 4; ++rt) Ot[rt] *= alpha;                    \
        }                                                                      \
        const float mL = m_i * L2E;                                            \
        f32x4 p[4];                                                            \
        _Pragma("unroll")                                                      \
        for (int rt = 0; rt < 4; ++rt) {                                       \
            f32x4 e = sv[rt] * L2E - mL;                                       \
            p[rt][0] = exp2fast(e[0]); p[rt][1] = exp2fast(e[1]);              \
            p[rt][2] = exp2fast(e[2]); p[rt][3] = exp2fast(e[3]);              \
        }                                                                      \
        li4 += (p[0] + p[1]) + (p[2] + p[3]);                                  \
        _Pragma("unroll")                                                      \
        for (int rt = 0; rt < 4; ++rt) {                                       \
            wq[rt][0] = cvtpk_bf16(p[rt][0], p[rt][1]);                        \
            wq[rt][1] = cvtpk_bf16(p[rt][2], p[rt][3]);                        \
        }                                                                      \
    }                                                                          \
    union { unsigned u[4]; short8 s; } pk0, pk1;                               \
    pk0.u[0] = wq[0][0]; pk0.u[1] = wq[0][1];                                  \
    pk0.u[2] = wq[1][0]; pk0.u[3] = wq[1][1];                                  \
    pk1.u[0] = wq[2][0]; pk1.u[1] = wq[2][1];                                  \
    pk1.u[2] = wq[3][0]; pk1.u[3] = wq[3][1];                                  \
    __builtin_amdgcn_s_setprio(1);                                             \
    _Pragma("unroll")                                                          \
    for (int rt = 0; rt < 4; ++rt) {                                           \
        Ot[rt] = __builtin_amdgcn_mfma_f32_16x16x32_bf16(vf[rt][0], pk0.s, Ot[rt], 0, 0, 0); \
        Ot[rt] = __builtin_amdgcn_mfma_f32_16x16x32_bf16(vf[rt][1], pk1.s, Ot[rt], 0, 0, 0); \
    }                                                                          \
    __builtin_amdgcn_s_setprio(0);                                             \
} while (0)

    for (int kt2 = 0; kt2 < 16; ++kt2) {
        ATTN_ITER(kt2 * 2,     0, brA, brB);
        ATTN_ITER(kt2 * 2 + 1, 1, brB, brA);
    }
#undef ATTN_ITER

    // epilogue
    float l_i = (li4[0] + li4[1]) + (li4[2] + li4[3]);
    l_i += __shfl_xor(l_i, 16);
    l_i += __shfl_xor(l_i, 32);
    const float inv = 1.f / l_i;
    const int q = q0 + l15;
#pragma unroll
    for (int rt = 0; rt < 4; ++rt) {
        u16x4 ob;
#pragma unroll
        for (int r = 0; r < 4; ++r) ob[r] = f2bf(Ot[rt][r] * inv);
        *(u16x4*)(AO + (size_t)(b * N_ + q) * D_ + h * DH_ + rt * 16 + qd * 4) = ob;
    }
}

// ---------------------------------------------------------------------------
extern "C" void kernel_launch(void* const* d_in, const int* in_sizes, int n_in,
                              void* d_out, int out_size, void* d_ws, size_t ws_size,
                              hipStream_t stream) {
    const float* x  = (const float*)d_in[0];
    const float* ab = (const float*)d_in[1];
    const float* Wq = (const float*)d_in[2];
    const float* bq = (const float*)d_in[3];
    const float* Wk = (const float*)d_in[4];
    const float* bk = (const float*)d_in[5];
    const float* Wv = (const float*)d_in[6];
    const float* bv = (const float*)d_in[7];
    const float* Wo = (const float*)d_in[8];
    const float* bo = (const float*)d_in[9];
    const float* qg = (const float*)d_in[10];
    const float* qb = (const float*)d_in[11];
    const float* kg = (const float*)d_in[12];
    const float* kb = (const float*)d_in[13];

    // ws layout (bf16 elements) -- xb eliminated (x converts inline in GEMM)
    unsigned short* Wb  = (unsigned short*)d_ws;                // [4][512][512]
    unsigned short* Y   = Wb  + (size_t)4 * D_ * D_;            // [3][8192][512]
    unsigned short* Kt  = Y   + (size_t)3 * M_ * D_;            // [4][8][32][64][64]
    unsigned short* Vt2 = Kt  + (size_t)M_ * D_;                // [4][8][32][64][64] (kv-permuted)
    unsigned short* AO  = Vt2 + (size_t)M_ * D_;                // [8192][512]
    float* out = (float*)d_out;

    // weights fp32 -> bf16 (small; x converts inline in the QKV GEMM)
    cvt_w<<<dim3(1024), dim3(256), 0, stream>>>(Wq, Wk, Wv, Wo, Wb);

    // QKV projection (A = fp32 x, inline cvt) with fused per-head LN on q,k
    gemm_nt<true, false, true><<<dim3(64, 12), dim3(256), 0, stream>>>(
        nullptr, x, Wb, bq, bk, bv, qg, qb, kg, kb, Y, nullptr);

    // pack K,V into contiguous per-head tiles (V transposed + kv-permuted)
    pack_kv<<<dim3(32, 4), dim3(256), 0, stream>>>(
        Y + (size_t)M_ * D_, Y + (size_t)2 * M_ * D_, Kt, Vt2);

    // attention (best-known attn12)
    attn12<<<dim3(16, 8, 4), dim3(512), 0, stream>>>(
        Y, Kt, Vt2, ab, AO);

    // output projection -> d_out (fp32)
    gemm_nt<false, true, false><<<dim3(64, 4), dim3(256), 0, stream>>>(
        AO, nullptr, Wb + (size_t)3 * D_ * D_, bo, bo, bo,
        nullptr, nullptr, nullptr, nullptr, nullptr, out);
}